// Round 1
// baseline (787.225 us; speedup 1.0000x reference)
//
#include <hip/hip_runtime.h>

// Shapes (fixed by the reference)
#define Bq 4
#define Lq 1024
#define Dq 1024
#define Hq 16
#define HDq 64
#define Fq 4096
#define Mq (Bq*Lq)   // 4096 rows of activations

typedef unsigned short u16;
using short8  = __attribute__((ext_vector_type(8))) short;
using floatx4 = __attribute__((ext_vector_type(4))) float;

__device__ __forceinline__ float b2f(u16 u) {
  union { unsigned int i; float f; } v; v.i = ((unsigned int)u) << 16; return v.f;
}
__device__ __forceinline__ u16 f2b(float f) {
  union { float f; unsigned int i; } v; v.f = f;
  unsigned int x = v.i;
  unsigned int r = x + 0x7fffu + ((x >> 16) & 1u);
  return (u16)(r >> 16);
}

// split f32 -> hi/lo bf16 pair (v ~= hi + lo, residual ~2^-18 |v|)
__device__ __forceinline__ void split2(float v, u16& hi, u16& lo) {
  hi = f2b(v);
  lo = f2b(v - b2f(hi));
}

// async global->LDS, 16B per lane (dest must be wave-uniform base + lane*16)
__device__ __forceinline__ void gl_lds16(const u16* g, u16* l) {
  __builtin_amdgcn_global_load_lds(
      (const __attribute__((address_space(1))) void*)g,
      (__attribute__((address_space(3))) void*)l, 16, 0, 0);
}

// ---------------------------------------------------------------------------
// f32 -> bf16 conversion. n4 must be a multiple of 4.
// ---------------------------------------------------------------------------
__launch_bounds__(256)
__global__ void cvt_f32_bf16(const float* __restrict__ s, u16* __restrict__ d, int n4) {
  const int i = (blockIdx.x * 256 + threadIdx.x) * 4;
  if (i < n4) {
    float4 v = *(const float4*)(s + i);
    ushort4 o;
    o.x = f2b(v.x); o.y = f2b(v.y); o.z = f2b(v.z); o.w = f2b(v.w);
    *(ushort4*)(d + i) = o;
  }
}

// ---------------------------------------------------------------------------
// GEMM: C[M,N] = A[M,K] * B[N,K]^T + bias[N]   (A,B bf16 K-contiguous,
// bias f32, C templated f32/bf16). 128x128 tile, BK=32, 4 waves,
// 4x4 16x16x32 bf16 MFMA. global_load_lds staging (m97-style, +35% vs reg).
// ---------------------------------------------------------------------------
template<bool RELU, typename OutT>
__launch_bounds__(256)
__global__ void gemm_bt(const u16* __restrict__ A, int lda,
                        const u16* __restrict__ B, int ldb,
                        const float* __restrict__ bias,
                        OutT* __restrict__ C, int ldc,
                        int K) {
  __shared__ __align__(16) u16 As[128 * 32];
  __shared__ __align__(16) u16 Bs[128 * 32];
  const int tid  = threadIdx.x;
  const int m0   = blockIdx.y * 128;
  const int n0   = blockIdx.x * 128;
  const int lane = tid & 63;
  const int wave = tid >> 6;
  const int wm   = (wave >> 1) * 64;
  const int wn   = (wave & 1) * 64;
  const int lrow = lane & 15;
  const int lk   = (lane >> 4) * 8;     // k-offset (elements) of this quad

  const int c0 = tid, c1 = tid + 256;
  const int ar0 = c0 >> 2, ac0 = (c0 & 3) * 8;
  const int ar1 = c1 >> 2, ac1 = (c1 & 3) * 8;

  floatx4 acc[4][4] = {};

  for (int k0 = 0; k0 < K; k0 += 32) {
    // async DMA: LDS byte addr = tid*16 (=wave_base + lane*16)  /  +4096 for c1
    gl_lds16(A + (size_t)(m0 + ar0) * lda + k0 + ac0, &As[c0 * 8]);
    gl_lds16(A + (size_t)(m0 + ar1) * lda + k0 + ac1, &As[c1 * 8]);
    gl_lds16(B + (size_t)(n0 + ar0) * ldb + k0 + ac0, &Bs[c0 * 8]);
    gl_lds16(B + (size_t)(n0 + ar1) * ldb + k0 + ac1, &Bs[c1 * 8]);
    __syncthreads();   // compiler drains vmcnt before s_barrier

    short8 af[4], bf[4];
#pragma unroll
    for (int t = 0; t < 4; ++t) {
      af[t] = *(const short8*)&As[(wm + t * 16 + lrow) * 32 + lk];
      bf[t] = *(const short8*)&Bs[(wn + t * 16 + lrow) * 32 + lk];
    }
#pragma unroll
    for (int i = 0; i < 4; ++i)
#pragma unroll
      for (int j = 0; j < 4; ++j)
        acc[i][j] = __builtin_amdgcn_mfma_f32_16x16x32_bf16(af[i], bf[j], acc[i][j], 0, 0, 0);
    __syncthreads();
  }

  // epilogue: D row = quad*4 + reg, col = lane&15  (verified m89/m91 layout)
#pragma unroll
  for (int i = 0; i < 4; ++i) {
    const int row = m0 + wm + i * 16 + (lane >> 4) * 4;
#pragma unroll
    for (int j = 0; j < 4; ++j) {
      const int col = n0 + wn + j * 16 + lrow;
      const float bv = bias[col];
#pragma unroll
      for (int r = 0; r < 4; ++r) {
        float v = acc[i][j][r] + bv;
        if (RELU) v = v > 0.f ? v : 0.f;
        if constexpr (sizeof(OutT) == 4) C[(size_t)(row + r) * ldc + col] = v;
        else                             C[(size_t)(row + r) * ldc + col] = f2b(v);
      }
    }
  }
}

// ---------------------------------------------------------------------------
// Transpose V slice of f32 QKV into bf16 Vt[b][h][d][kpos]
// ---------------------------------------------------------------------------
__launch_bounds__(256)
__global__ void transpose_v(const float* __restrict__ qkv, u16* __restrict__ vt) {
  __shared__ __align__(16) float t[64][65];
  const int kt = blockIdx.x;   // 16 k-tiles
  const int h  = blockIdx.y;   // 16 heads
  const int b  = blockIdx.z;   // 4 batch
  const int tid = threadIdx.x;
#pragma unroll
  for (int i = 0; i < 16; ++i) {
    int e = i * 256 + tid;
    int kk = e >> 6, d = e & 63;
    t[kk][d] = qkv[((size_t)(b * Lq + kt * 64 + kk)) * (3 * Dq) + 2 * Dq + h * HDq + d];
  }
  __syncthreads();
#pragma unroll
  for (int i = 0; i < 16; ++i) {
    int e = i * 256 + tid;
    int drow = e >> 6, kcol = e & 63;
    vt[(((size_t)(b * Hq + h)) * HDq + drow) * Lq + kt * 64 + kcol] = f2b(t[kcol][drow]);
  }
}

// ---------------------------------------------------------------------------
// Precompute K hi/lo bf16 split once (was done 64x redundantly per q-tile
// block inside attn_kernel). Layout: [b][h][k][d=64].
// ---------------------------------------------------------------------------
__launch_bounds__(256)
__global__ void split_k(const float* __restrict__ qkv,
                        u16* __restrict__ kh, u16* __restrict__ kl) {
  const int gid = blockIdx.x * 256 + threadIdx.x;   // 524288 total
  const int oct = gid & 7;            // d-octet
  const int l   = (gid >> 3) & 1023;
  const int h   = (gid >> 13) & 15;
  const int b   = gid >> 17;
  const float* src = qkv + ((size_t)(b * Lq + l)) * (3 * Dq) + Dq + h * HDq + oct * 8;
  float4 a = *(const float4*)src;
  float4 c = *(const float4*)(src + 4);
  float v[8] = {a.x, a.y, a.z, a.w, c.x, c.y, c.z, c.w};
  short8 hi, lo;
#pragma unroll
  for (int j = 0; j < 8; ++j) {
    u16 hh, ll; split2(v[j], hh, ll);
    hi[j] = (short)hh; lo[j] = (short)ll;
  }
  const size_t off = (((size_t)(b * Hq + h)) * Lq + l) * HDq + oct * 8;
  *(short8*)(kh + off) = hi;
  *(short8*)(kl + off) = lo;
}

// ---------------------------------------------------------------------------
// Fused attention. Q read f32 and split per-block (cheap: 16 rows); K hi/lo
// precomputed bf16. S in 64KB LDS, XOR-swizzled. attn_w written f32 into
// d_out; ctx bf16.
// ---------------------------------------------------------------------------
__device__ __forceinline__ int sw_idx(int m, int c) {
  return m * 1024 + (c ^ ((m & 3) * 8));
}

__device__ __forceinline__ void load_split8(const float* p, short8& hi, short8& lo) {
  float4 a = *(const float4*)p;
  float4 b = *(const float4*)(p + 4);
  float v[8] = {a.x, a.y, a.z, a.w, b.x, b.y, b.z, b.w};
#pragma unroll
  for (int j = 0; j < 8; ++j) {
    u16 h, l; split2(v[j], h, l);
    hi[j] = (short)h; lo[j] = (short)l;
  }
}

__launch_bounds__(256)
__global__ void attn_kernel(const float* __restrict__ qkv,
                            const u16* __restrict__ kh,
                            const u16* __restrict__ kl,
                            const u16* __restrict__ vt,
                            const float* __restrict__ mask,
                            float* __restrict__ attn_w,  // [B,H,L,L] f32 (d_out)
                            u16* __restrict__ ctx) {     // [B*L, D] bf16
  __shared__ __align__(16) float S[16 * 1024];   // 64KB exactly
  const int qt  = blockIdx.x;          // 64 q-tiles
  const int h   = blockIdx.y;
  const int b   = blockIdx.z;
  const int tid = threadIdx.x;
  const int lane = tid & 63, wave = tid >> 6;
  const int lrow = lane & 15, quad = lane >> 4;
  const int q0 = qt * 16;

  // --- phase 1: scores, split-precision QK^T ---
  const float* qbase = qkv + ((size_t)(b * Lq + q0 + lrow)) * (3 * Dq) + h * HDq + quad * 8;
  short8 aqh0, aql0, aqh1, aql1;
  load_split8(qbase,      aqh0, aql0);   // d = quad*8 + [0,8)
  load_split8(qbase + 32, aqh1, aql1);   // d = 32 + quad*8 + [0,8)

  const u16* khb = kh + (((size_t)(b * Hq + h)) * Lq) * HDq + quad * 8;
  const u16* klb = kl + (((size_t)(b * Hq + h)) * Lq) * HDq + quad * 8;
  for (int i = 0; i < 16; ++i) {
    const int n0 = wave * 256 + i * 16;
    const u16* kbh = khb + (size_t)(n0 + lrow) * HDq;
    const u16* kbl = klb + (size_t)(n0 + lrow) * HDq;
    short8 kh0 = *(const short8*)kbh;
    short8 kh1 = *(const short8*)(kbh + 32);
    short8 kl0 = *(const short8*)kbl;
    short8 kl1 = *(const short8*)(kbl + 32);
    floatx4 sc = {};
    sc = __builtin_amdgcn_mfma_f32_16x16x32_bf16(aqh0, kh0, sc, 0, 0, 0);
    sc = __builtin_amdgcn_mfma_f32_16x16x32_bf16(aqh0, kl0, sc, 0, 0, 0);
    sc = __builtin_amdgcn_mfma_f32_16x16x32_bf16(aql0, kh0, sc, 0, 0, 0);
    sc = __builtin_amdgcn_mfma_f32_16x16x32_bf16(aqh1, kh1, sc, 0, 0, 0);
    sc = __builtin_amdgcn_mfma_f32_16x16x32_bf16(aqh1, kl1, sc, 0, 0, 0);
    sc = __builtin_amdgcn_mfma_f32_16x16x32_bf16(aql1, kh1, sc, 0, 0, 0);
#pragma unroll
    for (int r = 0; r < 4; ++r)
      S[sw_idx(quad * 4 + r, n0 + lrow)] = sc[r] * 0.125f;
  }
  __syncthreads();

  // --- phase 2: softmax (16 threads per row, float4 chunks, exp once) ---
  const int row = tid >> 4, idx = tid & 15;
  const float* mrow = mask + (size_t)(q0 + row) * Lq;
  float mx = -1e30f;
#pragma unroll
  for (int j = 0; j < 16; ++j) {
    const int c = idx * 4 + j * 64;
    float* sp = &S[sw_idx(row, c)];           // 4 consecutive (XOR hits bits>=3)
    float4 v4 = *(const float4*)sp;
    float4 m4 = *(const float4*)(mrow + c);
    v4.x += m4.x; v4.y += m4.y; v4.z += m4.z; v4.w += m4.w;
    *(float4*)sp = v4;
    mx = fmaxf(mx, fmaxf(fmaxf(v4.x, v4.y), fmaxf(v4.z, v4.w)));
  }
#pragma unroll
  for (int s = 1; s < 16; s <<= 1) mx = fmaxf(mx, __shfl_xor(mx, s, 16));
  float sum = 0.f;
#pragma unroll
  for (int j = 0; j < 16; ++j) {
    const int c = idx * 4 + j * 64;
    float* sp = &S[sw_idx(row, c)];
    float4 v4 = *(const float4*)sp;
    float4 p;
    p.x = __expf(v4.x - mx); p.y = __expf(v4.y - mx);
    p.z = __expf(v4.z - mx); p.w = __expf(v4.w - mx);
    *(float4*)sp = p;                          // store exp, don't recompute
    sum += (p.x + p.y) + (p.z + p.w);
  }
#pragma unroll
  for (int s = 1; s < 16; s <<= 1) sum += __shfl_xor(sum, s, 16);
  const float scl = 1.f / sum;

  float* wrow = attn_w + (((size_t)(b * Hq + h)) * Lq + q0 + row) * Lq;
#pragma unroll
  for (int j = 0; j < 16; ++j) {
    const int c = idx * 4 + j * 64;
    float* sp = &S[sw_idx(row, c)];
    float4 p = *(const float4*)sp;
    p.x *= scl; p.y *= scl; p.z *= scl; p.w *= scl;
    *(float4*)sp = p;
    *(float4*)(wrow + c) = p;                  // 256B-contiguous per 16 lanes
  }
  __syncthreads();

  // --- phase 3: ctx = P @ V ; wave w owns d-range [w*16, w*16+16) ---
  const u16* vbase = vt + ((((size_t)(b * Hq + h)) * HDq) + wave * 16 + lrow) * Lq + quad * 8;
  floatx4 o = {};
  for (int kc = 0; kc < Lq; kc += 32) {
    const float* ps = &S[sw_idx(lrow, kc + quad * 8)];   // 8 consecutive floats
    float4 p0 = *(const float4*)ps;
    float4 p1 = *(const float4*)(ps + 4);
    short8 ap;
    ap[0] = (short)f2b(p0.x); ap[1] = (short)f2b(p0.y);
    ap[2] = (short)f2b(p0.z); ap[3] = (short)f2b(p0.w);
    ap[4] = (short)f2b(p1.x); ap[5] = (short)f2b(p1.y);
    ap[6] = (short)f2b(p1.z); ap[7] = (short)f2b(p1.w);
    short8 bv = *(const short8*)(vbase + kc);
    o = __builtin_amdgcn_mfma_f32_16x16x32_bf16(ap, bv, o, 0, 0, 0);
  }
#pragma unroll
  for (int r = 0; r < 4; ++r) {
    const int qrow = q0 + quad * 4 + r;
    ctx[((size_t)(b * Lq) + qrow) * Dq + h * HDq + wave * 16 + lrow] = f2b(o[r]);
  }
}

// ---------------------------------------------------------------------------
// Residual add + LayerNorm, one block per row of 1024, f32 math.
// a,res bf16; g,be f32; out templated (bf16 intermediate / f32 final).
// Safe for out == res.
// ---------------------------------------------------------------------------
template<typename OutT>
__launch_bounds__(256)
__global__ void add_ln(const u16* __restrict__ a, const u16* __restrict__ res,
                       const float* __restrict__ g, const float* __restrict__ be,
                       OutT* __restrict__ out) {
  const int rowi = blockIdx.x;
  const int tid = threadIdx.x;
  const u16* pa = a   + (size_t)rowi * Dq + tid * 4;
  const u16* pr = res + (size_t)rowi * Dq + tid * 4;
  ushort4 va = *(const ushort4*)pa;
  ushort4 vr = *(const ushort4*)pr;
  float v[4];
  float s = 0.f, s2 = 0.f;
#pragma unroll
  for (int j = 0; j < 4; ++j) {
    float x = b2f(((const u16*)&va)[j]) + b2f(((const u16*)&vr)[j]);
    v[j] = x; s += x; s2 += x * x;
  }
#pragma unroll
  for (int m = 1; m < 64; m <<= 1) { s += __shfl_xor(s, m, 64); s2 += __shfl_xor(s2, m, 64); }
  __shared__ float rs[4], rs2[4];
  const int wave = tid >> 6, lane = tid & 63;
  if (lane == 0) { rs[wave] = s; rs2[wave] = s2; }
  __syncthreads();
  s  = rs[0] + rs[1] + rs[2] + rs[3];
  s2 = rs2[0] + rs2[1] + rs2[2] + rs2[3];
  const float mean = s * (1.f / Dq);
  const float var  = s2 * (1.f / Dq) - mean * mean;
  const float rstd = rsqrtf(var + 1e-5f);
  float4 vg = *(const float4*)(g + tid * 4);
  float4 vb = *(const float4*)(be + tid * 4);
  float y0 = (v[0] - mean) * rstd * vg.x + vb.x;
  float y1 = (v[1] - mean) * rstd * vg.y + vb.y;
  float y2 = (v[2] - mean) * rstd * vg.z + vb.z;
  float y3 = (v[3] - mean) * rstd * vg.w + vb.w;
  if constexpr (sizeof(OutT) == 4) {
    float4 o = {y0, y1, y2, y3};
    *(float4*)(out + (size_t)rowi * Dq + tid * 4) = o;
  } else {
    ushort4 o;
    ((u16*)&o)[0] = f2b(y0); ((u16*)&o)[1] = f2b(y1);
    ((u16*)&o)[2] = f2b(y2); ((u16*)&o)[3] = f2b(y3);
    *(ushort4*)(out + (size_t)rowi * Dq + tid * 4) = o;
  }
}

// ---------------------------------------------------------------------------
extern "C" void kernel_launch(void* const* d_in, const int* in_sizes, int n_in,
                              void* d_out, int out_size, void* d_ws, size_t ws_size,
                              hipStream_t stream) {
  // Inputs are float32 (per the reference's setup_inputs).
  const float* x    = (const float*)d_in[0];
  const float* mask = (const float*)d_in[1];
  const float* win  = (const float*)d_in[2];
  const float* bin  = (const float*)d_in[3];
  const float* wo   = (const float*)d_in[4];
  const float* bo   = (const float*)d_in[5];
  const float* w1   = (const float*)d_in[6];
  const float* b1   = (const float*)d_in[7];
  const float* w2   = (const float*)d_in[8];
  const float* b2   = (const float*)d_in[9];
  const float* g1   = (const float*)d_in[10];
  const float* be1  = (const float*)d_in[11];
  const float* g2   = (const float*)d_in[12];
  const float* be2  = (const float*)d_in[13];

  // Outputs are float32 (reference output dtype).
  float* out0  = (float*)d_out;                       // [4,1024,1024]
  float* attnw = out0 + (size_t)Bq * Lq * Dq;         // [4,16,1024,1024]

  // Workspace layout (u16 units). Total 54,525,952 u16 = 104 MiB.
  u16*   ws   = (u16*)d_ws;
  u16*   xb   = ws;                                    // [0 .. 4.19M)
  float* qkvf = (float*)(ws + (size_t)4194304);        // f32 [4096,3072] = 25.17M u16
  u16*   vtb  = ws + (size_t)29360128;                 // 4.19M
  u16*   ctx  = ws + (size_t)33554432;                 // 4.19M
  u16*   aout = ws + (size_t)37748736;                 // 4.19M
  u16*   winb = ws + (size_t)41943040;                 // 3.15M
  u16*   wob  = ws + (size_t)45088768;                 // 1.05M
  u16*   w1b  = ws + (size_t)46137344;                 // 4.19M  (aliases Khi pre-lin1)
  u16*   w2b  = ws + (size_t)50331648;                 // 4.19M  (aliases Klo pre-lin2)
  u16*   y1   = aout;                                  // LN1 in-place over aout
  u16*   h1   = ws + (size_t)4194304;                  // aliases dead qkvf region
  u16*   ff   = ctx;                                   // aliases dead ctx
  u16*   khb  = w1b;   // K hi bf16 [b][h][k][64] — dead before w1 cvt
  u16*   klb  = w2b;   // K lo bf16 — dead before w2 cvt

  // 0. convert operands needed before/at QKV gemm
  cvt_f32_bf16<<<4194304 / 1024, 256, 0, stream>>>(x,   xb,   4194304);
  cvt_f32_bf16<<<3145728 / 1024, 256, 0, stream>>>(win, winb, 3145728);

  // 1. QKV = x @ Win^T + bin   -> f32 (precision for attn_w path)
  gemm_bt<false, float><<<dim3(3 * Dq / 128, Mq / 128), 256, 0, stream>>>(
      xb, Dq, winb, Dq, bin, qkvf, 3 * Dq, Dq);
  // 2. Vt (bf16) + K hi/lo split (once, not 64x per q-tile)
  transpose_v<<<dim3(16, Hq, Bq), 256, 0, stream>>>(qkvf, vtb);
  split_k<<<524288 / 256, 256, 0, stream>>>(qkvf, khb, klb);
  // 3. attention: attn_w (f32 -> d_out) and ctx (bf16)
  attn_kernel<<<dim3(Lq / 16, Hq, Bq), 256, 0, stream>>>(qkvf, khb, klb, vtb, mask, attnw, ctx);
  // 3b. convert remaining weights (khb/klb now dead; stream-serialized)
  cvt_f32_bf16<<<1048576 / 1024, 256, 0, stream>>>(wo,  wob,  1048576);
  cvt_f32_bf16<<<4194304 / 1024, 256, 0, stream>>>(w1,  w1b,  4194304);
  cvt_f32_bf16<<<4194304 / 1024, 256, 0, stream>>>(w2,  w2b,  4194304);
  // 4. out_proj
  gemm_bt<false, u16><<<dim3(Dq / 128, Mq / 128), 256, 0, stream>>>(
      ctx, Dq, wob, Dq, bo, aout, Dq, Dq);
  // 5. LN1(x + attn_out) -> y1 bf16 (in-place over aout)
  add_ln<u16><<<Mq, 256, 0, stream>>>(xb, aout, g1, be1, y1);
  // 6. lin1 + ReLU   (lin1_w is (F,D): ldb = Dq)
  gemm_bt<true, u16><<<dim3(Fq / 128, Mq / 128), 256, 0, stream>>>(
      y1, Dq, w1b, Dq, b1, h1, Fq, Dq);
  // 7. lin2          (lin2_w is (D,F): ldb = Fq)
  gemm_bt<false, u16><<<dim3(Dq / 128, Mq / 128), 256, 0, stream>>>(
      h1, Fq, w2b, Fq, b2, ff, Dq, Fq);
  // 8. LN2(y1 + ff) -> out0 (f32)
  add_ln<float><<<Mq, 256, 0, stream>>>(y1, ff, g2, be2, out0);
}

// Round 2
// 764.958 us; speedup vs baseline: 1.0291x; 1.0291x over previous
//
#include <hip/hip_runtime.h>

// Shapes (fixed by the reference)
#define Bq 4
#define Lq 1024
#define Dq 1024
#define Hq 16
#define HDq 64
#define Fq 4096
#define Mq (Bq*Lq)   // 4096 rows of activations

typedef unsigned short u16;
using short8  = __attribute__((ext_vector_type(8))) short;
using floatx4 = __attribute__((ext_vector_type(4))) float;

__device__ __forceinline__ float b2f(u16 u) {
  union { unsigned int i; float f; } v; v.i = ((unsigned int)u) << 16; return v.f;
}
__device__ __forceinline__ u16 f2b(float f) {
  union { float f; unsigned int i; } v; v.f = f;
  unsigned int x = v.i;
  unsigned int r = x + 0x7fffu + ((x >> 16) & 1u);
  return (u16)(r >> 16);
}

// split f32 -> hi/lo bf16 pair (v ~= hi + lo, residual ~2^-18 |v|)
__device__ __forceinline__ void split2(float v, u16& hi, u16& lo) {
  hi = f2b(v);
  lo = f2b(v - b2f(hi));
}

// async global->LDS, 16B per lane (dest must be wave-uniform base + lane*16)
__device__ __forceinline__ void gl_lds16(const u16* g, u16* l) {
  __builtin_amdgcn_global_load_lds(
      (const __attribute__((address_space(1))) void*)g,
      (__attribute__((address_space(3))) void*)l, 16, 0, 0);
}

// ---------------------------------------------------------------------------
// f32 -> bf16 conversion. n4 must be a multiple of 4.
// ---------------------------------------------------------------------------
__launch_bounds__(256)
__global__ void cvt_f32_bf16(const float* __restrict__ s, u16* __restrict__ d, int n4) {
  const int i = (blockIdx.x * 256 + threadIdx.x) * 4;
  if (i < n4) {
    float4 v = *(const float4*)(s + i);
    ushort4 o;
    o.x = f2b(v.x); o.y = f2b(v.y); o.z = f2b(v.z); o.w = f2b(v.w);
    *(ushort4*)(d + i) = o;
  }
}

// ---------------------------------------------------------------------------
// GEMM: C[M,N] = A[M,K] * B[N,K]^T + bias[N]   (A,B bf16 K-contiguous,
// bias f32, C templated f32/bf16). 128x128 tile, BK=32, 4 waves,
// 4x4 16x16x32 bf16 MFMA. global_load_lds staging (m97-style).
// ---------------------------------------------------------------------------
template<bool RELU, typename OutT>
__launch_bounds__(256)
__global__ void gemm_bt(const u16* __restrict__ A, int lda,
                        const u16* __restrict__ B, int ldb,
                        const float* __restrict__ bias,
                        OutT* __restrict__ C, int ldc,
                        int K) {
  __shared__ __align__(16) u16 As[128 * 32];
  __shared__ __align__(16) u16 Bs[128 * 32];
  const int tid  = threadIdx.x;
  const int m0   = blockIdx.y * 128;
  const int n0   = blockIdx.x * 128;
  const int lane = tid & 63;
  const int wave = tid >> 6;
  const int wm   = (wave >> 1) * 64;
  const int wn   = (wave & 1) * 64;
  const int lrow = lane & 15;
  const int lk   = (lane >> 4) * 8;     // k-offset (elements) of this quad

  const int c0 = tid, c1 = tid + 256;
  const int ar0 = c0 >> 2, ac0 = (c0 & 3) * 8;
  const int ar1 = c1 >> 2, ac1 = (c1 & 3) * 8;

  floatx4 acc[4][4] = {};

  for (int k0 = 0; k0 < K; k0 += 32) {
    gl_lds16(A + (size_t)(m0 + ar0) * lda + k0 + ac0, &As[c0 * 8]);
    gl_lds16(A + (size_t)(m0 + ar1) * lda + k0 + ac1, &As[c1 * 8]);
    gl_lds16(B + (size_t)(n0 + ar0) * ldb + k0 + ac0, &Bs[c0 * 8]);
    gl_lds16(B + (size_t)(n0 + ar1) * ldb + k0 + ac1, &Bs[c1 * 8]);
    __syncthreads();

    short8 af[4], bf[4];
#pragma unroll
    for (int t = 0; t < 4; ++t) {
      af[t] = *(const short8*)&As[(wm + t * 16 + lrow) * 32 + lk];
      bf[t] = *(const short8*)&Bs[(wn + t * 16 + lrow) * 32 + lk];
    }
#pragma unroll
    for (int i = 0; i < 4; ++i)
#pragma unroll
      for (int j = 0; j < 4; ++j)
        acc[i][j] = __builtin_amdgcn_mfma_f32_16x16x32_bf16(af[i], bf[j], acc[i][j], 0, 0, 0);
    __syncthreads();
  }

  // epilogue: D row = quad*4 + reg, col = lane&15  (verified m89/m91 layout)
#pragma unroll
  for (int i = 0; i < 4; ++i) {
    const int row = m0 + wm + i * 16 + (lane >> 4) * 4;
#pragma unroll
    for (int j = 0; j < 4; ++j) {
      const int col = n0 + wn + j * 16 + lrow;
      const float bv = bias[col];
#pragma unroll
      for (int r = 0; r < 4; ++r) {
        float v = acc[i][j][r] + bv;
        if (RELU) v = v > 0.f ? v : 0.f;
        if constexpr (sizeof(OutT) == 4) C[(size_t)(row + r) * ldc + col] = v;
        else                             C[(size_t)(row + r) * ldc + col] = f2b(v);
      }
    }
  }
}

// ---------------------------------------------------------------------------
// Transpose V slice of f32 QKV into bf16 Vt[b][h][d][kpos]
// ---------------------------------------------------------------------------
__launch_bounds__(256)
__global__ void transpose_v(const float* __restrict__ qkv, u16* __restrict__ vt) {
  __shared__ __align__(16) float t[64][65];
  const int kt = blockIdx.x;   // 16 k-tiles
  const int h  = blockIdx.y;   // 16 heads
  const int b  = blockIdx.z;   // 4 batch
  const int tid = threadIdx.x;
#pragma unroll
  for (int i = 0; i < 16; ++i) {
    int e = i * 256 + tid;
    int kk = e >> 6, d = e & 63;
    t[kk][d] = qkv[((size_t)(b * Lq + kt * 64 + kk)) * (3 * Dq) + 2 * Dq + h * HDq + d];
  }
  __syncthreads();
#pragma unroll
  for (int i = 0; i < 16; ++i) {
    int e = i * 256 + tid;
    int drow = e >> 6, kcol = e & 63;
    vt[(((size_t)(b * Hq + h)) * HDq + drow) * Lq + kt * 64 + kcol] = f2b(t[kcol][drow]);
  }
}

// ---------------------------------------------------------------------------
// Precompute K hi/lo bf16 split once. Layout: [b][h][k][d=64].
// ---------------------------------------------------------------------------
__launch_bounds__(256)
__global__ void split_k(const float* __restrict__ qkv,
                        u16* __restrict__ kh, u16* __restrict__ kl) {
  const int gid = blockIdx.x * 256 + threadIdx.x;   // 524288 total
  const int oct = gid & 7;            // d-octet
  const int l   = (gid >> 3) & 1023;
  const int h   = (gid >> 13) & 15;
  const int b   = gid >> 17;
  const float* src = qkv + ((size_t)(b * Lq + l)) * (3 * Dq) + Dq + h * HDq + oct * 8;
  float4 a = *(const float4*)src;
  float4 c = *(const float4*)(src + 4);
  float v[8] = {a.x, a.y, a.z, a.w, c.x, c.y, c.z, c.w};
  short8 hi, lo;
#pragma unroll
  for (int j = 0; j < 8; ++j) {
    u16 hh, ll; split2(v[j], hh, ll);
    hi[j] = (short)hh; lo[j] = (short)ll;
  }
  const size_t off = (((size_t)(b * Hq + h)) * Lq + l) * HDq + oct * 8;
  *(short8*)(kh + off) = hi;
  *(short8*)(kl + off) = lo;
}

// ---------------------------------------------------------------------------
// Fused attention, register-resident scores. 8 waves x 128-col strips.
// Scores never touch LDS as f32; softmax via width-16 shfl + 512B LDS
// exchange; attn_w written from registers; only bf16 P staged in LDS
// (32KB XOR-swizzled) for the PV phase (split-k across wave pairs).
// ---------------------------------------------------------------------------
__device__ __forceinline__ int ps_idx(int row, int col) {
  // [16][1024] bf16, 16B-slot XOR swizzle: slot ^= row&7
  return row * 1024 + ((((col >> 3) ^ (row & 7)) << 3) | (col & 7));
}

__device__ __forceinline__ void load_split8(const float* p, short8& hi, short8& lo) {
  float4 a = *(const float4*)p;
  float4 b = *(const float4*)(p + 4);
  float v[8] = {a.x, a.y, a.z, a.w, b.x, b.y, b.z, b.w};
#pragma unroll
  for (int j = 0; j < 8; ++j) {
    u16 h, l; split2(v[j], h, l);
    hi[j] = (short)h; lo[j] = (short)l;
  }
}

__launch_bounds__(512, 4)
__global__ void attn_kernel(const float* __restrict__ qkv,
                            const u16* __restrict__ kh,
                            const u16* __restrict__ kl,
                            const u16* __restrict__ vt,
                            const float* __restrict__ mask,
                            float* __restrict__ attn_w,  // [B,H,L,L] f32 (d_out)
                            u16* __restrict__ ctx) {     // [B*L, D] bf16
  __shared__ __align__(16) u16 Ps[16 * 1024];            // 32 KB bf16 P
  __shared__ float redmax[8][16];
  __shared__ float redsum[8][16];
  __shared__ float Pp[4][16][17];                        // phase-3 partials

  // XCD-chunked bijective swizzle: 4096 blocks, 8 XCDs, 512 per chunk.
  int lid = (int)blockIdx.x + ((int)blockIdx.y << 6) + ((int)blockIdx.z << 10);
  lid = (lid & 7) * 512 + (lid >> 3);
  const int qt = lid & 63, h = (lid >> 6) & 15, b = lid >> 10;
  const int bh = b * Hq + h;
  const int tid  = threadIdx.x;
  const int lane = tid & 63, wave = tid >> 6;   // wave 0..7
  const int lrow = lane & 15, quad = lane >> 4;
  const int q0 = qt * 16;

  // --- Q fragments (hi/lo split, f32-accurate logits) ---
  const float* qbase = qkv + ((size_t)(b * Lq + q0 + lrow)) * (3 * Dq) + h * HDq + quad * 8;
  short8 aqh0, aql0, aqh1, aql1;
  load_split8(qbase,      aqh0, aql0);
  load_split8(qbase + 32, aqh1, aql1);

  // --- phase 1: QK^T into registers, wave strip = 128 cols ---
  const u16* khb = kh + ((size_t)bh * Lq) * HDq + quad * 8;
  const u16* klb = kl + ((size_t)bh * Lq) * HDq + quad * 8;
  floatx4 sc[8];
#pragma unroll
  for (int i = 0; i < 8; ++i) {
    const int n0 = wave * 128 + i * 16;
    const u16* kbh = khb + (size_t)(n0 + lrow) * HDq;
    const u16* kbl = klb + (size_t)(n0 + lrow) * HDq;
    short8 k0h = *(const short8*)kbh;
    short8 k1h = *(const short8*)(kbh + 32);
    short8 k0l = *(const short8*)kbl;
    short8 k1l = *(const short8*)(kbl + 32);
    floatx4 s = {};
    s = __builtin_amdgcn_mfma_f32_16x16x32_bf16(aqh0, k0h, s, 0, 0, 0);
    s = __builtin_amdgcn_mfma_f32_16x16x32_bf16(aqh0, k0l, s, 0, 0, 0);
    s = __builtin_amdgcn_mfma_f32_16x16x32_bf16(aql0, k0h, s, 0, 0, 0);
    s = __builtin_amdgcn_mfma_f32_16x16x32_bf16(aqh1, k1h, s, 0, 0, 0);
    s = __builtin_amdgcn_mfma_f32_16x16x32_bf16(aqh1, k1l, s, 0, 0, 0);
    s = __builtin_amdgcn_mfma_f32_16x16x32_bf16(aql1, k1h, s, 0, 0, 0);
    sc[i] = s;
  }

  // --- scale + mask + row max (registers + shfl + 512B LDS exchange) ---
  const float* mbase = mask + (size_t)(q0 + quad * 4) * Lq + wave * 128 + lrow;
  float mx[4] = {-1e30f, -1e30f, -1e30f, -1e30f};
#pragma unroll
  for (int i = 0; i < 8; ++i)
#pragma unroll
    for (int r = 0; r < 4; ++r) {
      float v = sc[i][r] * 0.125f + mbase[(size_t)r * Lq + i * 16];
      sc[i][r] = v;
      mx[r] = fmaxf(mx[r], v);
    }
#pragma unroll
  for (int s = 1; s < 16; s <<= 1)
#pragma unroll
    for (int r = 0; r < 4; ++r) mx[r] = fmaxf(mx[r], __shfl_xor(mx[r], s, 16));
  if (lrow == 0) {
#pragma unroll
    for (int r = 0; r < 4; ++r) redmax[wave][quad * 4 + r] = mx[r];
  }
  __syncthreads();
  float M[4];
#pragma unroll
  for (int r = 0; r < 4; ++r) {
    float m = redmax[0][quad * 4 + r];
#pragma unroll
    for (int w = 1; w < 8; ++w) m = fmaxf(m, redmax[w][quad * 4 + r]);
    M[r] = m;
  }

  // --- exp + row sum ---
  float sm[4] = {0.f, 0.f, 0.f, 0.f};
#pragma unroll
  for (int i = 0; i < 8; ++i)
#pragma unroll
    for (int r = 0; r < 4; ++r) {
      float p = __expf(sc[i][r] - M[r]);
      sc[i][r] = p;
      sm[r] += p;
    }
#pragma unroll
  for (int s = 1; s < 16; s <<= 1)
#pragma unroll
    for (int r = 0; r < 4; ++r) sm[r] += __shfl_xor(sm[r], s, 16);
  if (lrow == 0) {
#pragma unroll
    for (int r = 0; r < 4; ++r) redsum[wave][quad * 4 + r] = sm[r];
  }
  __syncthreads();
  float scl[4];
#pragma unroll
  for (int r = 0; r < 4; ++r) {
    float t = redsum[0][quad * 4 + r];
#pragma unroll
    for (int w = 1; w < 8; ++w) t += redsum[w][quad * 4 + r];
    scl[r] = 1.f / t;
  }

  // --- write attn_w (f32, from regs) + stage P bf16 into swizzled LDS ---
  float* wbase = attn_w + ((size_t)bh * Lq + q0 + quad * 4) * Lq + wave * 128 + lrow;
#pragma unroll
  for (int i = 0; i < 8; ++i)
#pragma unroll
    for (int r = 0; r < 4; ++r) {
      float w = sc[i][r] * scl[r];
      wbase[(size_t)r * Lq + i * 16] = w;
      Ps[ps_idx(quad * 4 + r, wave * 128 + i * 16 + lrow)] = f2b(w);
    }
  __syncthreads();

  // --- phase 3: ctx = P @ V ; (wave&3) -> d-strip, (wave>>2) -> k-half ---
  const int dstrip = (wave & 3) * 16;
  const int khalf  = (wave >> 2) * 512;
  const u16* vbase = vt + ((size_t)bh * HDq + dstrip + lrow) * Lq + khalf + quad * 8;
  floatx4 o = {};
#pragma unroll
  for (int kc = 0; kc < 512; kc += 32) {
    short8 ap = *(const short8*)&Ps[ps_idx(lrow, khalf + kc + quad * 8)];
    short8 bv = *(const short8*)(vbase + kc);
    o = __builtin_amdgcn_mfma_f32_16x16x32_bf16(ap, bv, o, 0, 0, 0);
  }
  if (wave >= 4) {
#pragma unroll
    for (int r = 0; r < 4; ++r) Pp[wave - 4][quad * 4 + r][lrow] = o[r];
  }
  __syncthreads();
  if (wave < 4) {
#pragma unroll
    for (int r = 0; r < 4; ++r) {
      float v = o[r] + Pp[wave][quad * 4 + r][lrow];
      ctx[((size_t)(b * Lq) + q0 + quad * 4 + r) * Dq + h * HDq + dstrip + lrow] = f2b(v);
    }
  }
}

// ---------------------------------------------------------------------------
// Residual add + LayerNorm, one block per row of 1024, f32 math.
// ---------------------------------------------------------------------------
template<typename OutT>
__launch_bounds__(256)
__global__ void add_ln(const u16* __restrict__ a, const u16* __restrict__ res,
                       const float* __restrict__ g, const float* __restrict__ be,
                       OutT* __restrict__ out) {
  const int rowi = blockIdx.x;
  const int tid = threadIdx.x;
  const u16* pa = a   + (size_t)rowi * Dq + tid * 4;
  const u16* pr = res + (size_t)rowi * Dq + tid * 4;
  ushort4 va = *(const ushort4*)pa;
  ushort4 vr = *(const ushort4*)pr;
  float v[4];
  float s = 0.f, s2 = 0.f;
#pragma unroll
  for (int j = 0; j < 4; ++j) {
    float x = b2f(((const u16*)&va)[j]) + b2f(((const u16*)&vr)[j]);
    v[j] = x; s += x; s2 += x * x;
  }
#pragma unroll
  for (int m = 1; m < 64; m <<= 1) { s += __shfl_xor(s, m, 64); s2 += __shfl_xor(s2, m, 64); }
  __shared__ float rs[4], rs2[4];
  const int wave = tid >> 6, lane = tid & 63;
  if (lane == 0) { rs[wave] = s; rs2[wave] = s2; }
  __syncthreads();
  s  = rs[0] + rs[1] + rs[2] + rs[3];
  s2 = rs2[0] + rs2[1] + rs2[2] + rs2[3];
  const float mean = s * (1.f / Dq);
  const float var  = s2 * (1.f / Dq) - mean * mean;
  const float rstd = rsqrtf(var + 1e-5f);
  float4 vg = *(const float4*)(g + tid * 4);
  float4 vb = *(const float4*)(be + tid * 4);
  float y0 = (v[0] - mean) * rstd * vg.x + vb.x;
  float y1 = (v[1] - mean) * rstd * vg.y + vb.y;
  float y2 = (v[2] - mean) * rstd * vg.z + vb.z;
  float y3 = (v[3] - mean) * rstd * vg.w + vb.w;
  if constexpr (sizeof(OutT) == 4) {
    float4 o = {y0, y1, y2, y3};
    *(float4*)(out + (size_t)rowi * Dq + tid * 4) = o;
  } else {
    ushort4 o;
    ((u16*)&o)[0] = f2b(y0); ((u16*)&o)[1] = f2b(y1);
    ((u16*)&o)[2] = f2b(y2); ((u16*)&o)[3] = f2b(y3);
    *(ushort4*)(out + (size_t)rowi * Dq + tid * 4) = o;
  }
}

// ---------------------------------------------------------------------------
extern "C" void kernel_launch(void* const* d_in, const int* in_sizes, int n_in,
                              void* d_out, int out_size, void* d_ws, size_t ws_size,
                              hipStream_t stream) {
  const float* x    = (const float*)d_in[0];
  const float* mask = (const float*)d_in[1];
  const float* win  = (const float*)d_in[2];
  const float* bin  = (const float*)d_in[3];
  const float* wo   = (const float*)d_in[4];
  const float* bo   = (const float*)d_in[5];
  const float* w1   = (const float*)d_in[6];
  const float* b1   = (const float*)d_in[7];
  const float* w2   = (const float*)d_in[8];
  const float* b2   = (const float*)d_in[9];
  const float* g1   = (const float*)d_in[10];
  const float* be1  = (const float*)d_in[11];
  const float* g2   = (const float*)d_in[12];
  const float* be2  = (const float*)d_in[13];

  float* out0  = (float*)d_out;                       // [4,1024,1024]
  float* attnw = out0 + (size_t)Bq * Lq * Dq;         // [4,16,1024,1024]

  // Workspace layout (u16 units). Total 54,525,952 u16 = 104 MiB.
  u16*   ws   = (u16*)d_ws;
  u16*   xb   = ws;                                    // [0 .. 4.19M)
  float* qkvf = (float*)(ws + (size_t)4194304);        // f32 [4096,3072] = 25.17M u16
  u16*   vtb  = ws + (size_t)29360128;                 // 4.19M
  u16*   ctx  = ws + (size_t)33554432;                 // 4.19M
  u16*   aout = ws + (size_t)37748736;                 // 4.19M
  u16*   winb = ws + (size_t)41943040;                 // 3.15M
  u16*   wob  = ws + (size_t)45088768;                 // 1.05M
  u16*   w1b  = ws + (size_t)46137344;                 // 4.19M  (aliases Khi pre-lin1)
  u16*   w2b  = ws + (size_t)50331648;                 // 4.19M  (aliases Klo pre-lin2)
  u16*   y1   = aout;                                  // LN1 in-place over aout
  u16*   h1   = ws + (size_t)4194304;                  // aliases dead qkvf region
  u16*   ff   = ctx;                                   // aliases dead ctx
  u16*   khb  = w1b;   // K hi bf16 [b][h][k][64] — dead before w1 cvt
  u16*   klb  = w2b;   // K lo bf16 — dead before w2 cvt

  // 0. convert operands needed before/at QKV gemm
  cvt_f32_bf16<<<4194304 / 1024, 256, 0, stream>>>(x,   xb,   4194304);
  cvt_f32_bf16<<<3145728 / 1024, 256, 0, stream>>>(win, winb, 3145728);

  // 1. QKV = x @ Win^T + bin   -> f32 (precision for attn_w path)
  gemm_bt<false, float><<<dim3(3 * Dq / 128, Mq / 128), 256, 0, stream>>>(
      xb, Dq, winb, Dq, bin, qkvf, 3 * Dq, Dq);
  // 2. Vt (bf16) + K hi/lo split
  transpose_v<<<dim3(16, Hq, Bq), 256, 0, stream>>>(qkvf, vtb);
  split_k<<<524288 / 256, 256, 0, stream>>>(qkvf, khb, klb);
  // 3. attention: attn_w (f32 -> d_out) and ctx (bf16)
  attn_kernel<<<dim3(Lq / 16, Hq, Bq), 512, 0, stream>>>(qkvf, khb, klb, vtb, mask, attnw, ctx);
  // 3b. convert remaining weights (khb/klb now dead; stream-serialized)
  cvt_f32_bf16<<<1048576 / 1024, 256, 0, stream>>>(wo,  wob,  1048576);
  cvt_f32_bf16<<<4194304 / 1024, 256, 0, stream>>>(w1,  w1b,  4194304);
  cvt_f32_bf16<<<4194304 / 1024, 256, 0, stream>>>(w2,  w2b,  4194304);
  // 4. out_proj
  gemm_bt<false, u16><<<dim3(Dq / 128, Mq / 128), 256, 0, stream>>>(
      ctx, Dq, wob, Dq, bo, aout, Dq, Dq);
  // 5. LN1(x + attn_out) -> y1 bf16 (in-place over aout)
  add_ln<u16><<<Mq, 256, 0, stream>>>(xb, aout, g1, be1, y1);
  // 6. lin1 + ReLU   (lin1_w is (F,D): ldb = Dq)
  gemm_bt<true, u16><<<dim3(Fq / 128, Mq / 128), 256, 0, stream>>>(
      y1, Dq, w1b, Dq, b1, h1, Fq, Dq);
  // 7. lin2          (lin2_w is (D,F): ldb = Fq)
  gemm_bt<false, u16><<<dim3(Dq / 128, Mq / 128), 256, 0, stream>>>(
      h1, Fq, w2b, Fq, b2, ff, Dq, Fq);
  // 8. LN2(y1 + ff) -> out0 (f32)
  add_ln<float><<<Mq, 256, 0, stream>>>(y1, ff, g2, be2, out0);
}

// Round 3
// 732.393 us; speedup vs baseline: 1.0749x; 1.0445x over previous
//
#include <hip/hip_runtime.h>

// Shapes (fixed by the reference)
#define Bq 4
#define Lq 1024
#define Dq 1024
#define Hq 16
#define HDq 64
#define Fq 4096
#define Mq (Bq*Lq)   // 4096 rows of activations

typedef unsigned short u16;
using short8  = __attribute__((ext_vector_type(8))) short;
using floatx4 = __attribute__((ext_vector_type(4))) float;

__device__ __forceinline__ float b2f(u16 u) {
  union { unsigned int i; float f; } v; v.i = ((unsigned int)u) << 16; return v.f;
}
__device__ __forceinline__ u16 f2b(float f) {
  union { float f; unsigned int i; } v; v.f = f;
  unsigned int x = v.i;
  unsigned int r = x + 0x7fffu + ((x >> 16) & 1u);
  return (u16)(r >> 16);
}

// split f32 -> hi/lo bf16 pair (v ~= hi + lo, residual ~2^-18 |v|)
__device__ __forceinline__ void split2(float v, u16& hi, u16& lo) {
  hi = f2b(v);
  lo = f2b(v - b2f(hi));
}

// async global->LDS, 16B per lane (dest must be wave-uniform base + lane*16)
__device__ __forceinline__ void gl_lds16(const u16* g, u16* l) {
  __builtin_amdgcn_global_load_lds(
      (const __attribute__((address_space(1))) void*)g,
      (__attribute__((address_space(3))) void*)l, 16, 0, 0);
}

// ---------------------------------------------------------------------------
// f32 -> bf16 conversion. n4 must be a multiple of 4.
// ---------------------------------------------------------------------------
__launch_bounds__(256)
__global__ void cvt_f32_bf16(const float* __restrict__ s, u16* __restrict__ d, int n4) {
  const int i = (blockIdx.x * 256 + threadIdx.x) * 4;
  if (i < n4) {
    float4 v = *(const float4*)(s + i);
    ushort4 o;
    o.x = f2b(v.x); o.y = f2b(v.y); o.z = f2b(v.z); o.w = f2b(v.w);
    *(ushort4*)(d + i) = o;
  }
}

// ---------------------------------------------------------------------------
// GEMM: C[M,N] = A[M,K] * B[N,K]^T + bias[N]   (A,B bf16 K-contiguous,
// bias f32, C templated f32/bf16). 128x128 tile, BK=32, 4 waves,
// 4x4 16x16x32 bf16 MFMA. global_load_lds staging (m97-style).
// ---------------------------------------------------------------------------
template<bool RELU, typename OutT>
__launch_bounds__(256)
__global__ void gemm_bt(const u16* __restrict__ A, int lda,
                        const u16* __restrict__ B, int ldb,
                        const float* __restrict__ bias,
                        OutT* __restrict__ C, int ldc,
                        int K) {
  __shared__ __align__(16) u16 As[128 * 32];
  __shared__ __align__(16) u16 Bs[128 * 32];
  const int tid  = threadIdx.x;
  const int m0   = blockIdx.y * 128;
  const int n0   = blockIdx.x * 128;
  const int lane = tid & 63;
  const int wave = tid >> 6;
  const int wm   = (wave >> 1) * 64;
  const int wn   = (wave & 1) * 64;
  const int lrow = lane & 15;
  const int lk   = (lane >> 4) * 8;     // k-offset (elements) of this quad

  const int c0 = tid, c1 = tid + 256;
  const int ar0 = c0 >> 2, ac0 = (c0 & 3) * 8;
  const int ar1 = c1 >> 2, ac1 = (c1 & 3) * 8;

  floatx4 acc[4][4] = {};

  for (int k0 = 0; k0 < K; k0 += 32) {
    gl_lds16(A + (size_t)(m0 + ar0) * lda + k0 + ac0, &As[c0 * 8]);
    gl_lds16(A + (size_t)(m0 + ar1) * lda + k0 + ac1, &As[c1 * 8]);
    gl_lds16(B + (size_t)(n0 + ar0) * ldb + k0 + ac0, &Bs[c0 * 8]);
    gl_lds16(B + (size_t)(n0 + ar1) * ldb + k0 + ac1, &Bs[c1 * 8]);
    __syncthreads();

    short8 af[4], bf[4];
#pragma unroll
    for (int t = 0; t < 4; ++t) {
      af[t] = *(const short8*)&As[(wm + t * 16 + lrow) * 32 + lk];
      bf[t] = *(const short8*)&Bs[(wn + t * 16 + lrow) * 32 + lk];
    }
#pragma unroll
    for (int i = 0; i < 4; ++i)
#pragma unroll
      for (int j = 0; j < 4; ++j)
        acc[i][j] = __builtin_amdgcn_mfma_f32_16x16x32_bf16(af[i], bf[j], acc[i][j], 0, 0, 0);
    __syncthreads();
  }

  // epilogue: D row = quad*4 + reg, col = lane&15  (verified m89/m91 layout)
#pragma unroll
  for (int i = 0; i < 4; ++i) {
    const int row = m0 + wm + i * 16 + (lane >> 4) * 4;
#pragma unroll
    for (int j = 0; j < 4; ++j) {
      const int col = n0 + wn + j * 16 + lrow;
      const float bv = bias[col];
#pragma unroll
      for (int r = 0; r < 4; ++r) {
        float v = acc[i][j][r] + bv;
        if (RELU) v = v > 0.f ? v : 0.f;
        if constexpr (sizeof(OutT) == 4) C[(size_t)(row + r) * ldc + col] = v;
        else                             C[(size_t)(row + r) * ldc + col] = f2b(v);
      }
    }
  }
}

// ---------------------------------------------------------------------------
// Split-K GEMM variant: blockIdx.z selects a K-slice of length KS; writes
// f32 partials (no bias, no relu) to P0/P1. Doubles occupancy for the
// N=1024 GEMMs (out_proj, lin2) that otherwise run 1 block/CU.
// ---------------------------------------------------------------------------
template<int KS>
__launch_bounds__(256)
__global__ void gemm_bt_ks(const u16* __restrict__ A, int lda,
                           const u16* __restrict__ B, int ldb,
                           float* __restrict__ P0, float* __restrict__ P1,
                           int ldc) {
  __shared__ __align__(16) u16 As[128 * 32];
  __shared__ __align__(16) u16 Bs[128 * 32];
  const int z = blockIdx.z;
  A += (size_t)z * KS;
  B += (size_t)z * KS;
  float* C = z ? P1 : P0;

  const int tid  = threadIdx.x;
  const int m0   = blockIdx.y * 128;
  const int n0   = blockIdx.x * 128;
  const int lane = tid & 63;
  const int wave = tid >> 6;
  const int wm   = (wave >> 1) * 64;
  const int wn   = (wave & 1) * 64;
  const int lrow = lane & 15;
  const int lk   = (lane >> 4) * 8;

  const int c0 = tid, c1 = tid + 256;
  const int ar0 = c0 >> 2, ac0 = (c0 & 3) * 8;
  const int ar1 = c1 >> 2, ac1 = (c1 & 3) * 8;

  floatx4 acc[4][4] = {};

  for (int k0 = 0; k0 < KS; k0 += 32) {
    gl_lds16(A + (size_t)(m0 + ar0) * lda + k0 + ac0, &As[c0 * 8]);
    gl_lds16(A + (size_t)(m0 + ar1) * lda + k0 + ac1, &As[c1 * 8]);
    gl_lds16(B + (size_t)(n0 + ar0) * ldb + k0 + ac0, &Bs[c0 * 8]);
    gl_lds16(B + (size_t)(n0 + ar1) * ldb + k0 + ac1, &Bs[c1 * 8]);
    __syncthreads();

    short8 af[4], bf[4];
#pragma unroll
    for (int t = 0; t < 4; ++t) {
      af[t] = *(const short8*)&As[(wm + t * 16 + lrow) * 32 + lk];
      bf[t] = *(const short8*)&Bs[(wn + t * 16 + lrow) * 32 + lk];
    }
#pragma unroll
    for (int i = 0; i < 4; ++i)
#pragma unroll
      for (int j = 0; j < 4; ++j)
        acc[i][j] = __builtin_amdgcn_mfma_f32_16x16x32_bf16(af[i], bf[j], acc[i][j], 0, 0, 0);
    __syncthreads();
  }

#pragma unroll
  for (int i = 0; i < 4; ++i) {
    const int row = m0 + wm + i * 16 + (lane >> 4) * 4;
#pragma unroll
    for (int j = 0; j < 4; ++j) {
      const int col = n0 + wn + j * 16 + lrow;
#pragma unroll
      for (int r = 0; r < 4; ++r)
        C[(size_t)(row + r) * ldc + col] = acc[i][j][r];
    }
  }
}

// ---------------------------------------------------------------------------
// Transpose V slice of f32 QKV into bf16 Vt[b][h][d][kpos]
// ---------------------------------------------------------------------------
__launch_bounds__(256)
__global__ void transpose_v(const float* __restrict__ qkv, u16* __restrict__ vt) {
  __shared__ __align__(16) float t[64][65];
  const int kt = blockIdx.x;   // 16 k-tiles
  const int h  = blockIdx.y;   // 16 heads
  const int b  = blockIdx.z;   // 4 batch
  const int tid = threadIdx.x;
#pragma unroll
  for (int i = 0; i < 16; ++i) {
    int e = i * 256 + tid;
    int kk = e >> 6, d = e & 63;
    t[kk][d] = qkv[((size_t)(b * Lq + kt * 64 + kk)) * (3 * Dq) + 2 * Dq + h * HDq + d];
  }
  __syncthreads();
#pragma unroll
  for (int i = 0; i < 16; ++i) {
    int e = i * 256 + tid;
    int drow = e >> 6, kcol = e & 63;
    vt[(((size_t)(b * Hq + h)) * HDq + drow) * Lq + kt * 64 + kcol] = f2b(t[kcol][drow]);
  }
}

// ---------------------------------------------------------------------------
// Precompute K hi/lo bf16 split once. Layout: [b][h][k][d=64].
// ---------------------------------------------------------------------------
__launch_bounds__(256)
__global__ void split_k(const float* __restrict__ qkv,
                        u16* __restrict__ kh, u16* __restrict__ kl) {
  const int gid = blockIdx.x * 256 + threadIdx.x;   // 524288 total
  const int oct = gid & 7;            // d-octet
  const int l   = (gid >> 3) & 1023;
  const int h   = (gid >> 13) & 15;
  const int b   = gid >> 17;
  const float* src = qkv + ((size_t)(b * Lq + l)) * (3 * Dq) + Dq + h * HDq + oct * 8;
  float4 a = *(const float4*)src;
  float4 c = *(const float4*)(src + 4);
  float v[8] = {a.x, a.y, a.z, a.w, c.x, c.y, c.z, c.w};
  short8 hi, lo;
#pragma unroll
  for (int j = 0; j < 8; ++j) {
    u16 hh, ll; split2(v[j], hh, ll);
    hi[j] = (short)hh; lo[j] = (short)ll;
  }
  const size_t off = (((size_t)(b * Hq + h)) * Lq + l) * HDq + oct * 8;
  *(short8*)(kh + off) = hi;
  *(short8*)(kl + off) = lo;
}

// ---------------------------------------------------------------------------
// Fused attention, register-resident scores. 8 waves x 128-col strips.
// attn_w global stores DEFERRED past the Ps barrier so the barrier's
// vmcnt(0) drain doesn't serialize on 64KB of scattered stores; they
// overlap PV compute instead.
// ---------------------------------------------------------------------------
__device__ __forceinline__ int ps_idx(int row, int col) {
  // [16][1024] bf16, 16B-slot XOR swizzle: slot ^= row&7
  return row * 1024 + ((((col >> 3) ^ (row & 7)) << 3) | (col & 7));
}

__device__ __forceinline__ void load_split8(const float* p, short8& hi, short8& lo) {
  float4 a = *(const float4*)p;
  float4 b = *(const float4*)(p + 4);
  float v[8] = {a.x, a.y, a.z, a.w, b.x, b.y, b.z, b.w};
#pragma unroll
  for (int j = 0; j < 8; ++j) {
    u16 h, l; split2(v[j], h, l);
    hi[j] = (short)h; lo[j] = (short)l;
  }
}

__launch_bounds__(512, 4)
__global__ void attn_kernel(const float* __restrict__ qkv,
                            const u16* __restrict__ kh,
                            const u16* __restrict__ kl,
                            const u16* __restrict__ vt,
                            const float* __restrict__ mask,
                            float* __restrict__ attn_w,  // [B,H,L,L] f32 (d_out)
                            u16* __restrict__ ctx) {     // [B*L, D] bf16
  __shared__ __align__(16) u16 Ps[16 * 1024];            // 32 KB bf16 P
  __shared__ float redmax[8][16];
  __shared__ float redsum[8][16];
  __shared__ float Pp[4][16][17];                        // phase-3 partials

  // XCD-chunked bijective swizzle: 4096 blocks, 8 XCDs, 512 per chunk.
  int lid = (int)blockIdx.x + ((int)blockIdx.y << 6) + ((int)blockIdx.z << 10);
  lid = (lid & 7) * 512 + (lid >> 3);
  const int qt = lid & 63, h = (lid >> 6) & 15, b = lid >> 10;
  const int bh = b * Hq + h;
  const int tid  = threadIdx.x;
  const int lane = tid & 63, wave = tid >> 6;   // wave 0..7
  const int lrow = lane & 15, quad = lane >> 4;
  const int q0 = qt * 16;

  // --- Q fragments (hi/lo split, f32-accurate logits) ---
  const float* qbase = qkv + ((size_t)(b * Lq + q0 + lrow)) * (3 * Dq) + h * HDq + quad * 8;
  short8 aqh0, aql0, aqh1, aql1;
  load_split8(qbase,      aqh0, aql0);
  load_split8(qbase + 32, aqh1, aql1);

  // --- phase 1: QK^T into registers, wave strip = 128 cols ---
  const u16* khb = kh + ((size_t)bh * Lq) * HDq + quad * 8;
  const u16* klb = kl + ((size_t)bh * Lq) * HDq + quad * 8;
  floatx4 sc[8];
#pragma unroll
  for (int i = 0; i < 8; ++i) {
    const int n0 = wave * 128 + i * 16;
    const u16* kbh = khb + (size_t)(n0 + lrow) * HDq;
    const u16* kbl = klb + (size_t)(n0 + lrow) * HDq;
    short8 k0h = *(const short8*)kbh;
    short8 k1h = *(const short8*)(kbh + 32);
    short8 k0l = *(const short8*)kbl;
    short8 k1l = *(const short8*)(kbl + 32);
    floatx4 s = {};
    s = __builtin_amdgcn_mfma_f32_16x16x32_bf16(aqh0, k0h, s, 0, 0, 0);
    s = __builtin_amdgcn_mfma_f32_16x16x32_bf16(aqh0, k0l, s, 0, 0, 0);
    s = __builtin_amdgcn_mfma_f32_16x16x32_bf16(aql0, k0h, s, 0, 0, 0);
    s = __builtin_amdgcn_mfma_f32_16x16x32_bf16(aqh1, k1h, s, 0, 0, 0);
    s = __builtin_amdgcn_mfma_f32_16x16x32_bf16(aqh1, k1l, s, 0, 0, 0);
    s = __builtin_amdgcn_mfma_f32_16x16x32_bf16(aql1, k1h, s, 0, 0, 0);
    sc[i] = s;
  }

  // --- scale + mask + row max ---
  const float* mbase = mask + (size_t)(q0 + quad * 4) * Lq + wave * 128 + lrow;
  float mx[4] = {-1e30f, -1e30f, -1e30f, -1e30f};
#pragma unroll
  for (int i = 0; i < 8; ++i)
#pragma unroll
    for (int r = 0; r < 4; ++r) {
      float v = sc[i][r] * 0.125f + mbase[(size_t)r * Lq + i * 16];
      sc[i][r] = v;
      mx[r] = fmaxf(mx[r], v);
    }
#pragma unroll
  for (int s = 1; s < 16; s <<= 1)
#pragma unroll
    for (int r = 0; r < 4; ++r) mx[r] = fmaxf(mx[r], __shfl_xor(mx[r], s, 16));
  if (lrow == 0) {
#pragma unroll
    for (int r = 0; r < 4; ++r) redmax[wave][quad * 4 + r] = mx[r];
  }
  __syncthreads();
  float M[4];
#pragma unroll
  for (int r = 0; r < 4; ++r) {
    float m = redmax[0][quad * 4 + r];
#pragma unroll
    for (int w = 1; w < 8; ++w) m = fmaxf(m, redmax[w][quad * 4 + r]);
    M[r] = m;
  }

  // --- exp + row sum ---
  float sm[4] = {0.f, 0.f, 0.f, 0.f};
#pragma unroll
  for (int i = 0; i < 8; ++i)
#pragma unroll
    for (int r = 0; r < 4; ++r) {
      float p = __expf(sc[i][r] - M[r]);
      sc[i][r] = p;
      sm[r] += p;
    }
#pragma unroll
  for (int s = 1; s < 16; s <<= 1)
#pragma unroll
    for (int r = 0; r < 4; ++r) sm[r] += __shfl_xor(sm[r], s, 16);
  if (lrow == 0) {
#pragma unroll
    for (int r = 0; r < 4; ++r) redsum[wave][quad * 4 + r] = sm[r];
  }
  __syncthreads();
  float scl[4];
#pragma unroll
  for (int r = 0; r < 4; ++r) {
    float t = redsum[0][quad * 4 + r];
#pragma unroll
    for (int w = 1; w < 8; ++w) t += redsum[w][quad * 4 + r];
    scl[r] = 1.f / t;
  }

  // --- normalize in regs + stage P bf16 into swizzled LDS ---
#pragma unroll
  for (int i = 0; i < 8; ++i)
#pragma unroll
    for (int r = 0; r < 4; ++r) {
      float w = sc[i][r] * scl[r];
      sc[i][r] = w;                         // keep for deferred global store
      Ps[ps_idx(quad * 4 + r, wave * 128 + i * 16 + lrow)] = f2b(w);
    }
  __syncthreads();   // drains only ds_writes (global stores not yet issued)

  // --- deferred attn_w stores: overlap with PV below ---
  float* wbase = attn_w + ((size_t)bh * Lq + q0 + quad * 4) * Lq + wave * 128 + lrow;
#pragma unroll
  for (int i = 0; i < 8; ++i)
#pragma unroll
    for (int r = 0; r < 4; ++r)
      wbase[(size_t)r * Lq + i * 16] = sc[i][r];

  // --- phase 3: ctx = P @ V ; (wave&3) -> d-strip, (wave>>2) -> k-half ---
  const int dstrip = (wave & 3) * 16;
  const int khalf  = (wave >> 2) * 512;
  const u16* vbase = vt + ((size_t)bh * HDq + dstrip + lrow) * Lq + khalf + quad * 8;
  floatx4 o = {};
#pragma unroll
  for (int kc = 0; kc < 512; kc += 32) {
    short8 ap = *(const short8*)&Ps[ps_idx(lrow, khalf + kc + quad * 8)];
    short8 bv = *(const short8*)(vbase + kc);
    o = __builtin_amdgcn_mfma_f32_16x16x32_bf16(ap, bv, o, 0, 0, 0);
  }
  if (wave >= 4) {
#pragma unroll
    for (int r = 0; r < 4; ++r) Pp[wave - 4][quad * 4 + r][lrow] = o[r];
  }
  __syncthreads();
  if (wave < 4) {
#pragma unroll
    for (int r = 0; r < 4; ++r) {
      float v = o[r] + Pp[wave][quad * 4 + r][lrow];
      ctx[((size_t)(b * Lq) + q0 + quad * 4 + r) * Dq + h * HDq + dstrip + lrow] = f2b(v);
    }
  }
}

// ---------------------------------------------------------------------------
// Residual add + split-K reduce + bias + LayerNorm (fused).
// in = b2f(res[j]) + p0[j] + p1[j] + bias[col]; LN over row of 1024.
// ---------------------------------------------------------------------------
template<typename OutT>
__launch_bounds__(256)
__global__ void add_ln_red(const u16* __restrict__ res,
                           const float* __restrict__ p0,
                           const float* __restrict__ p1,
                           const float* __restrict__ bias,
                           const float* __restrict__ g, const float* __restrict__ be,
                           OutT* __restrict__ out) {
  const int rowi = blockIdx.x;
  const int tid = threadIdx.x;
  const size_t off = (size_t)rowi * Dq + tid * 4;
  ushort4 vr = *(const ushort4*)(res + off);
  float4 a0 = *(const float4*)(p0 + off);
  float4 a1 = *(const float4*)(p1 + off);
  float4 bb = *(const float4*)(bias + tid * 4);
  float v[4];
  v[0] = b2f(vr.x) + a0.x + a1.x + bb.x;
  v[1] = b2f(vr.y) + a0.y + a1.y + bb.y;
  v[2] = b2f(vr.z) + a0.z + a1.z + bb.z;
  v[3] = b2f(vr.w) + a0.w + a1.w + bb.w;
  float s = 0.f, s2 = 0.f;
#pragma unroll
  for (int j = 0; j < 4; ++j) { s += v[j]; s2 += v[j] * v[j]; }
#pragma unroll
  for (int m = 1; m < 64; m <<= 1) { s += __shfl_xor(s, m, 64); s2 += __shfl_xor(s2, m, 64); }
  __shared__ float rs[4], rs2[4];
  const int wave = tid >> 6, lane = tid & 63;
  if (lane == 0) { rs[wave] = s; rs2[wave] = s2; }
  __syncthreads();
  s  = rs[0] + rs[1] + rs[2] + rs[3];
  s2 = rs2[0] + rs2[1] + rs2[2] + rs2[3];
  const float mean = s * (1.f / Dq);
  const float var  = s2 * (1.f / Dq) - mean * mean;
  const float rstd = rsqrtf(var + 1e-5f);
  float4 vg = *(const float4*)(g + tid * 4);
  float4 vb = *(const float4*)(be + tid * 4);
  float y0 = (v[0] - mean) * rstd * vg.x + vb.x;
  float y1 = (v[1] - mean) * rstd * vg.y + vb.y;
  float y2 = (v[2] - mean) * rstd * vg.z + vb.z;
  float y3 = (v[3] - mean) * rstd * vg.w + vb.w;
  if constexpr (sizeof(OutT) == 4) {
    float4 o = {y0, y1, y2, y3};
    *(float4*)(out + off) = o;
  } else {
    ushort4 o;
    ((u16*)&o)[0] = f2b(y0); ((u16*)&o)[1] = f2b(y1);
    ((u16*)&o)[2] = f2b(y2); ((u16*)&o)[3] = f2b(y3);
    *(ushort4*)(out + off) = o;
  }
}

// ---------------------------------------------------------------------------
extern "C" void kernel_launch(void* const* d_in, const int* in_sizes, int n_in,
                              void* d_out, int out_size, void* d_ws, size_t ws_size,
                              hipStream_t stream) {
  const float* x    = (const float*)d_in[0];
  const float* mask = (const float*)d_in[1];
  const float* win  = (const float*)d_in[2];
  const float* bin  = (const float*)d_in[3];
  const float* wo   = (const float*)d_in[4];
  const float* bo   = (const float*)d_in[5];
  const float* w1   = (const float*)d_in[6];
  const float* b1   = (const float*)d_in[7];
  const float* w2   = (const float*)d_in[8];
  const float* b2   = (const float*)d_in[9];
  const float* g1   = (const float*)d_in[10];
  const float* be1  = (const float*)d_in[11];
  const float* g2   = (const float*)d_in[12];
  const float* be2  = (const float*)d_in[13];

  float* out0  = (float*)d_out;                       // [4,1024,1024]
  float* attnw = out0 + (size_t)Bq * Lq * Dq;         // [4,16,1024,1024]

  // Workspace layout (u16 units). Total 54,525,952 u16 = 104 MiB.
  u16*   ws   = (u16*)d_ws;
  u16*   xb   = ws;                                    // [0 .. 4.19M)
  float* qkvf = (float*)(ws + (size_t)4194304);        // f32 [4096,3072] = 25.17M u16
  u16*   vtb  = ws + (size_t)29360128;                 // 4.19M
  u16*   ctx  = ws + (size_t)33554432;                 // 4.19M
  u16*   aout = ws + (size_t)37748736;                 // 4.19M (y1 lives here)
  u16*   winb = ws + (size_t)41943040;                 // 3.15M
  u16*   wob  = ws + (size_t)45088768;                 // 1.05M
  u16*   w1b  = ws + (size_t)46137344;                 // 4.19M  (aliases Khi pre-lin1)
  u16*   w2b  = ws + (size_t)50331648;                 // 4.19M  (aliases Klo pre-lin2)
  u16*   y1   = aout;
  u16*   h1   = ws + (size_t)4194304;                  // lin1 out [4096,4096] bf16, ends at 20.97M
  u16*   khb  = w1b;   // K hi bf16 [b][h][k][64] — dead before w1 cvt
  u16*   klb  = w2b;   // K lo bf16 — dead before w2 cvt
  // split-K f32 partial buffers (16.8MB each), in regions dead at use time:
  float* poA = (float*)(ws + (size_t)4194304);         // out_proj z=0 (dead qkvf)
  float* poB = (float*)(ws + (size_t)12582912);        // out_proj z=1 (dead qkvf)
  float* plA = (float*)(ws + (size_t)20971520);        // lin2 z=0 (qkvf tail past h1)
  float* plB = (float*)(ws + (size_t)29360128);        // lin2 z=1 (dead vtb+ctx)

  // 0. convert operands needed before/at QKV gemm
  cvt_f32_bf16<<<4194304 / 1024, 256, 0, stream>>>(x,   xb,   4194304);
  cvt_f32_bf16<<<3145728 / 1024, 256, 0, stream>>>(win, winb, 3145728);

  // 1. QKV = x @ Win^T + bin   -> f32 (precision for attn_w path)
  gemm_bt<false, float><<<dim3(3 * Dq / 128, Mq / 128), 256, 0, stream>>>(
      xb, Dq, winb, Dq, bin, qkvf, 3 * Dq, Dq);
  // 2. Vt (bf16) + K hi/lo split
  transpose_v<<<dim3(16, Hq, Bq), 256, 0, stream>>>(qkvf, vtb);
  split_k<<<524288 / 256, 256, 0, stream>>>(qkvf, khb, klb);
  // 3. attention: attn_w (f32 -> d_out) and ctx (bf16)
  attn_kernel<<<dim3(Lq / 16, Hq, Bq), 512, 0, stream>>>(qkvf, khb, klb, vtb, mask, attnw, ctx);
  // 3b. convert remaining weights (khb/klb now dead; stream-serialized)
  cvt_f32_bf16<<<1048576 / 1024, 256, 0, stream>>>(wo,  wob,  1048576);
  cvt_f32_bf16<<<4194304 / 1024, 256, 0, stream>>>(w1,  w1b,  4194304);
  cvt_f32_bf16<<<4194304 / 1024, 256, 0, stream>>>(w2,  w2b,  4194304);
  // 4. out_proj, split-K=2 (K slices of 512) -> f32 partials
  gemm_bt_ks<512><<<dim3(Dq / 128, Mq / 128, 2), 256, 0, stream>>>(
      ctx, Dq, wob, Dq, poA, poB, Dq);
  // 5. LN1(x + (poA+poB+bo)) -> y1 bf16
  add_ln_red<u16><<<Mq, 256, 0, stream>>>(xb, poA, poB, bo, g1, be1, y1);
  // 6. lin1 + ReLU   (lin1_w is (F,D): ldb = Dq)
  gemm_bt<true, u16><<<dim3(Fq / 128, Mq / 128), 256, 0, stream>>>(
      y1, Dq, w1b, Dq, b1, h1, Fq, Dq);
  // 7. lin2, split-K=2 (K slices of 2048) -> f32 partials
  gemm_bt_ks<2048><<<dim3(Dq / 128, Mq / 128, 2), 256, 0, stream>>>(
      h1, Fq, w2b, Fq, plA, plB, Dq);
  // 8. LN2(y1 + (plA+plB+b2)) -> out0 (f32)
  add_ln_red<float><<<Mq, 256, 0, stream>>>(y1, plA, plB, b2, g2, be2, out0);
}